// Round 1
// baseline (245.225 us; speedup 1.0000x reference)
//
#include <hip/hip_runtime.h>
#include <cmath>

typedef __bf16 bf16x8 __attribute__((ext_vector_type(8)));
typedef float f32x4 __attribute__((ext_vector_type(4)));
typedef unsigned int u32x4 __attribute__((ext_vector_type(4)));

#define SEQ 2048
#define EMBED 768
#define NHEAD 12
#define HDIM 64
#define NTOK 4096            // BS*SEQ
// scale = 1/sqrt(768); ref masks with -1e20 BEFORE scaling, so masked logit = -1e20*scale
#define SCALE_Q 0.036084391824351615f
#define NEGBIG (-3.6084391824351614e18f)

// ---------- helpers ----------
__device__ __forceinline__ void gload_lds16(const __bf16* g, __bf16* l) {
  __builtin_amdgcn_global_load_lds(
      (const __attribute__((address_space(1))) void*)g,
      (__attribute__((address_space(3))) void*)l, 16, 0, 0);
}

__device__ __forceinline__ unsigned pack2(float a, float b) {
  unsigned short lo = __builtin_bit_cast(unsigned short, (__bf16)a);
  unsigned short hi = __builtin_bit_cast(unsigned short, (__bf16)b);
  return (unsigned)lo | ((unsigned)hi << 16);
}

// ---------- fp32 -> bf16 converts (G13: vectorized) ----------
__global__ __launch_bounds__(256) void cvt_qkv(const float* __restrict__ Q,
                                               const float* __restrict__ K,
                                               const float* __restrict__ V,
                                               __bf16* __restrict__ Qb,
                                               __bf16* __restrict__ Kb,
                                               __bf16* __restrict__ Vb) {
  const float* s = blockIdx.y == 0 ? Q : blockIdx.y == 1 ? K : V;
  __bf16* d = blockIdx.y == 0 ? Qb : blockIdx.y == 1 ? Kb : Vb;
  size_t i = ((size_t)blockIdx.x * 256 + threadIdx.x) * 8;
  float4 a = *(const float4*)(s + i);
  float4 c = *(const float4*)(s + i + 4);
  bf16x8 r;
  r[0] = (__bf16)a.x; r[1] = (__bf16)a.y; r[2] = (__bf16)a.z; r[3] = (__bf16)a.w;
  r[4] = (__bf16)c.x; r[5] = (__bf16)c.y; r[6] = (__bf16)c.z; r[7] = (__bf16)c.w;
  *(bf16x8*)(d + i) = r;
}

__global__ __launch_bounds__(256) void cvt_w(const float* __restrict__ W0,
                                             const float* __restrict__ W1,
                                             const float* __restrict__ W2,
                                             const float* __restrict__ W3,
                                             __bf16* __restrict__ O0,
                                             __bf16* __restrict__ O1,
                                             __bf16* __restrict__ O2,
                                             __bf16* __restrict__ O3) {
  const float* s = blockIdx.y == 0 ? W0 : blockIdx.y == 1 ? W1 : blockIdx.y == 2 ? W2 : W3;
  __bf16* d = blockIdx.y == 0 ? O0 : blockIdx.y == 1 ? O1 : blockIdx.y == 2 ? O2 : O3;
  size_t i = ((size_t)blockIdx.x * 256 + threadIdx.x) * 8;
  float4 a = *(const float4*)(s + i);
  float4 c = *(const float4*)(s + i + 4);
  bf16x8 r;
  r[0] = (__bf16)a.x; r[1] = (__bf16)a.y; r[2] = (__bf16)a.z; r[3] = (__bf16)a.w;
  r[4] = (__bf16)c.x; r[5] = (__bf16)c.y; r[6] = (__bf16)c.z; r[7] = (__bf16)c.w;
  *(bf16x8*)(d + i) = r;
}

// ---------- mask -> bitmask (32 u64 per row) ----------
__global__ __launch_bounds__(256) void pack_mask_k(const int* __restrict__ mask,
                                                   unsigned long long* __restrict__ bits) {
  int e = blockIdx.x * 256 + threadIdx.x;
  unsigned long long b = __ballot(mask[e] != 0);
  if ((threadIdx.x & 63) == 0) bits[e >> 6] = b;
}

// ---------- m97-structure GEMM: C[m][n] = alpha * sum_k A[m,k]*B[n,k], K=768 ----------
template <typename CT>
__device__ __forceinline__ void gemm_body(const __bf16* __restrict__ A,
                                          const __bf16* __restrict__ B,
                                          CT* __restrict__ C, int N, int row0,
                                          int col0, float alpha, __bf16* As,
                                          __bf16* Bs) {
  const int K = EMBED;
  const int tid = threadIdx.x;
  const int lane = tid & 63;
  const int wave = tid >> 6;
  const int wr = wave >> 1, wc = wave & 1;
  const int l15 = lane & 15, g = lane >> 4;
  f32x4 acc[4][4] = {};

  // staging: thread t covers LDS bytes [t*16, t*16+16) of an 8KB tile (row-major [128][32] bf16)
  const __bf16* aS = A + (size_t)(row0 + (tid >> 2)) * K + (tid & 3) * 8;
  const __bf16* bS = B + (size_t)(col0 + (tid >> 2)) * K + (tid & 3) * 8;
  __bf16* aL = As + wave * 512;  // 1KB per wave
  __bf16* bL = Bs + wave * 512;

  for (int k0 = 0; k0 < K; k0 += 32) {
    __syncthreads();  // previous iter's ds_reads done before overwrite
    gload_lds16(aS + k0, aL);                              // rows 0..63
    gload_lds16(aS + k0 + (size_t)64 * K, aL + 2048);      // rows 64..127
    gload_lds16(bS + k0, bL);
    gload_lds16(bS + k0 + (size_t)64 * K, bL + 2048);
    __syncthreads();  // staging visible
    bf16x8 af[4], bfr[4];
#pragma unroll
    for (int i = 0; i < 4; ++i)
      af[i] = *(const bf16x8*)(As + (wr * 64 + i * 16 + l15) * 32 + g * 8);
#pragma unroll
    for (int j = 0; j < 4; ++j)
      bfr[j] = *(const bf16x8*)(Bs + (wc * 64 + j * 16 + l15) * 32 + g * 8);
#pragma unroll
    for (int i = 0; i < 4; ++i)
#pragma unroll
      for (int j = 0; j < 4; ++j)
        acc[i][j] = __builtin_amdgcn_mfma_f32_16x16x32_bf16(af[i], bfr[j],
                                                            acc[i][j], 0, 0, 0);
  }
  // epilogue: C/D layout col=lane&15 (n), row=(lane>>4)*4+reg (m)  [m89]
#pragma unroll
  for (int i = 0; i < 4; ++i)
#pragma unroll
    for (int j = 0; j < 4; ++j) {
      size_t base = (size_t)(row0 + wr * 64 + i * 16 + g * 4) * N + col0 +
                    wc * 64 + j * 16 + l15;
#pragma unroll
      for (int r = 0; r < 4; ++r)
        C[base + (size_t)r * N] = (CT)(alpha * acc[i][j][r]);
    }
}

// q/k projections (N=768) + transposed v projection (vT[hd][tok], N=4096) in one launch
__global__ __launch_bounds__(256) void gemm_qkv(
    const __bf16* __restrict__ Qb, const __bf16* __restrict__ Kb,
    const __bf16* __restrict__ Vb, const __bf16* __restrict__ Wqb,
    const __bf16* __restrict__ Wkb, const __bf16* __restrict__ Wvb,
    __bf16* __restrict__ qh, __bf16* __restrict__ kh, __bf16* __restrict__ vT) {
  __shared__ __align__(16) __bf16 As[128 * 32];
  __shared__ __align__(16) __bf16 Bs[128 * 32];
  if (blockIdx.z == 0)
    gemm_body<__bf16>(Qb, Wqb, qh, EMBED, blockIdx.x * 128, blockIdx.y * 128,
                      SCALE_Q, As, Bs);  // scale folded into q
  else if (blockIdx.z == 1)
    gemm_body<__bf16>(Kb, Wkb, kh, EMBED, blockIdx.x * 128, blockIdx.y * 128,
                      1.f, As, Bs);
  else
    gemm_body<__bf16>(Wvb, Vb, vT, NTOK, blockIdx.y * 128, blockIdx.x * 128,
                      1.f, As, Bs);  // vT[m=hd][n=b*S+s]
}

__global__ __launch_bounds__(256) void gemm_out(const __bf16* __restrict__ AO,
                                                const __bf16* __restrict__ Wob,
                                                float* __restrict__ out) {
  __shared__ __align__(16) __bf16 As[128 * 32];
  __shared__ __align__(16) __bf16 Bs[128 * 32];
  gemm_body<float>(AO, Wob, out, EMBED, blockIdx.x * 128, blockIdx.y * 128, 1.f,
                   As, Bs);
}

// ---------- flash attention, swapped-QK^T (S^T = K·Q^T), KV tile = 64 ----------
// block: 4 waves, 64 q-rows; wave w owns q rows [q0+16w, +16); lane's q = lane&15
__global__ __launch_bounds__(256) void flash_attn(
    const __bf16* __restrict__ qh, const __bf16* __restrict__ kh,
    const __bf16* __restrict__ vT, const unsigned long long* __restrict__ mbits,
    __bf16* __restrict__ AO) {
  __shared__ __align__(16) __bf16 plds[4][16 * 72];  // per-wave P^T round-trip, padded
  const int tid = threadIdx.x;
  const int lane = tid & 63, w = tid >> 6;
  const int l15 = lane & 15, G = lane >> 4;
  const int bh = blockIdx.y, b = bh / NHEAD, h = bh % NHEAD;
  const int qrow = blockIdx.x * 64 + w * 16 + l15;  // seq position 0..2047

  // Q fragments hoisted (already scaled by 1/sqrt(768) in projection)
  const __bf16* qptr = qh + ((size_t)b * SEQ + qrow) * EMBED + h * HDIM + G * 8;
  bf16x8 qf0 = *(const bf16x8*)qptr;
  bf16x8 qf1 = *(const bf16x8*)(qptr + 32);

  float m_run = -INFINITY, l_run = 0.f;
  f32x4 o[4] = {};  // o[dt][r] = O[q=l15][d = dt*16 + G*4 + r]
  unsigned* plu = (unsigned*)&plds[w][0];
  const unsigned* pluc = (const unsigned*)&plds[w][0];
  const __bf16* pl = &plds[w][0];

  const __bf16* kbase = kh + (size_t)b * SEQ * EMBED + h * HDIM + G * 8;
  const __bf16* vbase = vT + ((size_t)h * HDIM + l15) * NTOK + b * SEQ + G * 8;
  const unsigned long long* mrow = mbits + (size_t)qrow * (SEQ / 64);

  for (int t = 0; t < SEQ / 64; ++t) {
    unsigned long long mb = mrow[t];
    // S^T: lane holds S[q=l15][kv = t*64 + j*16 + G*4 + r]
    f32x4 s[4];
#pragma unroll
    for (int j = 0; j < 4; ++j) {
      const __bf16* kp = kbase + (size_t)(t * 64 + j * 16 + l15) * EMBED;
      bf16x8 kf0 = *(const bf16x8*)kp;
      bf16x8 kf1 = *(const bf16x8*)(kp + 32);
      f32x4 z = {};
      z = __builtin_amdgcn_mfma_f32_16x16x32_bf16(kf0, qf0, z, 0, 0, 0);
      z = __builtin_amdgcn_mfma_f32_16x16x32_bf16(kf1, qf1, z, 0, 0, 0);
      s[j] = z;
    }
    // mask (ref semantics: masked logit == -1e20/sqrt(768)) + per-q max
    float mx = -INFINITY;
#pragma unroll
    for (int j = 0; j < 4; ++j)
#pragma unroll
      for (int r = 0; r < 4; ++r) {
        int kvi = j * 16 + G * 4 + r;
        float val = ((mb >> kvi) & 1ULL) ? s[j][r] : NEGBIG;
        s[j][r] = val;
        mx = fmaxf(mx, val);
      }
    mx = fmaxf(mx, __shfl_xor(mx, 16));
    mx = fmaxf(mx, __shfl_xor(mx, 32));
    float m_new = fmaxf(m_run, mx);
    float fac = __expf(m_run - m_new);  // first tile: exp(-inf)=0
    float ls = 0.f;
#pragma unroll
    for (int j = 0; j < 4; ++j)
#pragma unroll
      for (int r = 0; r < 4; ++r) {
        float p = __expf(s[j][r] - m_new);
        s[j][r] = p;
        ls += p;
      }
    ls += __shfl_xor(ls, 16);
    ls += __shfl_xor(ls, 32);
    l_run = l_run * fac + ls;
    m_run = m_new;
#pragma unroll
    for (int dt = 0; dt < 4; ++dt) o[dt] *= fac;

    // P^T -> LDS (u32 bf16-pairs), rows=q (stride 72 elems), cols=kv
#pragma unroll
    for (int j = 0; j < 4; ++j) {
      plu[l15 * 36 + j * 8 + G * 2] = pack2(s[j][0], s[j][1]);
      plu[l15 * 36 + j * 8 + G * 2 + 1] = pack2(s[j][2], s[j][3]);
    }
    // PV: O^T(16d x 16q) += V^T(16d x 32kv) · P^T(32kv x 16q); same-wave DS ordered
#pragma unroll
    for (int ks = 0; ks < 2; ++ks) {
      int ridx = l15 * 36 + ks * 16 + G * 4;
      u32x4 traw = {pluc[ridx], pluc[ridx + 1], pluc[ridx + 2], pluc[ridx + 3]};
      bf16x8 pf = __builtin_bit_cast(bf16x8, traw);
#pragma unroll
      for (int dt = 0; dt < 4; ++dt) {
        bf16x8 vf =
            *(const bf16x8*)(vbase + (size_t)dt * 16 * NTOK + t * 64 + ks * 32);
        o[dt] = __builtin_amdgcn_mfma_f32_16x16x32_bf16(vf, pf, o[dt], 0, 0, 0);
      }
    }
    (void)pl;
  }
  float inv = 1.f / l_run;
  unsigned* aout = (unsigned*)(AO + ((size_t)b * SEQ + qrow) * EMBED + h * HDIM);
#pragma unroll
  for (int dt = 0; dt < 4; ++dt) {
    aout[(dt * 16 + G * 4) >> 1] = pack2(o[dt][0] * inv, o[dt][1] * inv);
    aout[((dt * 16 + G * 4) >> 1) + 1] = pack2(o[dt][2] * inv, o[dt][3] * inv);
  }
}

// ---------- launch ----------
extern "C" void kernel_launch(void* const* d_in, const int* in_sizes, int n_in,
                              void* d_out, int out_size, void* d_ws,
                              size_t ws_size, hipStream_t stream) {
  const float* Q = (const float*)d_in[0];
  const float* K = (const float*)d_in[1];
  const float* V = (const float*)d_in[2];
  const int* mask = (const int*)d_in[3];
  const float* Wq = (const float*)d_in[4];
  const float* Wk = (const float*)d_in[5];
  const float* Wv = (const float*)d_in[6];
  const float* Wo = (const float*)d_in[7];
  float* out = (float*)d_out;

  char* ws = (char*)d_ws;
  size_t off = 0;
  auto alloc = [&](size_t bytes) {
    char* p = ws + off;
    off += (bytes + 255) & ~(size_t)255;
    return p;
  };
  const size_t ACT = (size_t)NTOK * EMBED * 2;   // 6.29 MB bf16
  const size_t WMT = (size_t)EMBED * EMBED * 2;  // 1.18 MB bf16
  __bf16* Qb = (__bf16*)alloc(ACT);
  __bf16* Kb = (__bf16*)alloc(ACT);
  __bf16* Vb = (__bf16*)alloc(ACT);
  __bf16* Wqb = (__bf16*)alloc(WMT);
  __bf16* Wkb = (__bf16*)alloc(WMT);
  __bf16* Wvb = (__bf16*)alloc(WMT);
  __bf16* Wob = (__bf16*)alloc(WMT);
  __bf16* qh = (__bf16*)alloc(ACT);
  __bf16* kh = (__bf16*)alloc(ACT);
  __bf16* vT = (__bf16*)alloc(ACT);
  __bf16* AO = (__bf16*)alloc(ACT);
  unsigned long long* mbits =
      (unsigned long long*)alloc((size_t)SEQ * (SEQ / 64) * 8);  // 512 KB

  cvt_qkv<<<dim3(NTOK * EMBED / 2048, 3), 256, 0, stream>>>(Q, K, V, Qb, Kb, Vb);
  cvt_w<<<dim3(EMBED * EMBED / 2048, 4), 256, 0, stream>>>(Wq, Wk, Wv, Wo, Wqb,
                                                           Wkb, Wvb, Wob);
  pack_mask_k<<<dim3(SEQ * SEQ / 256), 256, 0, stream>>>(mask, mbits);
  gemm_qkv<<<dim3(NTOK / 128, EMBED / 128, 3), 256, 0, stream>>>(
      Qb, Kb, Vb, Wqb, Wkb, Wvb, qh, kh, vT);
  flash_attn<<<dim3(SEQ / 64, 2 * NHEAD), 256, 0, stream>>>(qh, kh, vT, mbits, AO);
  gemm_out<<<dim3(NTOK / 128, EMBED / 128), 256, 0, stream>>>(AO, Wob, out);
  (void)in_sizes; (void)n_in; (void)out_size; (void)ws_size;
}